// Round 16
// baseline (1368.171 us; speedup 1.0000x reference)
//
#include <hip/hip_runtime.h>

// LSTMForecaster: B=4096, T=512, D=1, H=64, 2 layers + FC(64->1).
// R17 = R16 (champion, 493us) with TWO INDEPENDENT BLOCKS PER CU.
//   R16 accounting: step 2311 cyc = 466 MFMA + ~585 VALU + ~1260 stall; all
//   intra-block scheduling knobs exhausted (R11-R15). The stall can only be
//   filled by INDEPENDENT work -> co-resident blocks on disjoint batches.
//   NB 16->8, grid 256->512 (2 blocks/CU, 24 waves, 6/SIMD; launch_bounds
//   (768,6) caps VGPR at ~85, current 68 fits). Blocks share nothing; each
//   fills the other's dependency stalls. Cost: B-frag cols 8-15 wasted
//   (2x MFMA + 2x cell issue per useful batch) -> aggregate issue ~1050
//   cyc/step-equiv, still under the old 2311 wall.
//   Lanes with m>=8 compute garbage: writes land in dummy ring rows 8-15,
//   NaN stays column-isolated in MFMA; outputs read only rows/cols 0-7.
//   Math byte-identical to R16 (absmax 6.1e-5): single-term bf16 W, bf16 h,
//   exp2-folded scales, packed cells, free-running flag sync.

#define TT 512
#define HH 64
#define NB 8          // batches per block (halved)
#define RR 16         // ring rows (16 so m=0..15 lanes have a legal row)
#define XP 516

typedef __bf16 bf16_t;
typedef bf16_t bf16x8 __attribute__((ext_vector_type(8)));
typedef float  f32x4  __attribute__((ext_vector_type(4)));
typedef float  f32x2  __attribute__((ext_vector_type(2)));

#define MFMA(A, B, C) __builtin_amdgcn_mfma_f32_16x16x32_bf16((A), (B), (C), 0, 0, 0)
#define RCPF(x) __builtin_amdgcn_rcpf(x)

#if __has_builtin(__builtin_amdgcn_exp2f)
#define EXP2F(x) __builtin_amdgcn_exp2f(x)
#else
__device__ __forceinline__ float EXP2F(float x) {
    float r;
    asm volatile("v_exp_f32 %0, %1" : "=v"(r) : "v"(x));
    return r;
}
#endif

#define SC_IFO (-1.4426950408889634f)   // -log2(e)
#define SC_G   ( 2.8853900817779268f)   // +2*log2(e)

__device__ __forceinline__ unsigned short f32_to_bf16_rne(float f) {
    unsigned int u = __builtin_bit_cast(unsigned int, f);
    unsigned int r = u + 0x7fffu + ((u >> 16) & 1u);
    return (unsigned short)(r >> 16);
}
__device__ __forceinline__ bf16_t bits_to_bf16(unsigned short u) {
    return __builtin_bit_cast(bf16_t, u);
}
// single-term weight frag with per-row scale folded in (RNE)
__device__ __forceinline__ void build_frag_scaled(const float* __restrict__ p, float sc,
                                                  bf16x8& w) {
    const float4 a = *(const float4*)p;
    const float4 b = *(const float4*)(p + 4);
    float v[8] = {a.x, a.y, a.z, a.w, b.x, b.y, b.z, b.w};
#pragma unroll
    for (int jj = 0; jj < 8; ++jj)
        w[jj] = bits_to_bf16(f32_to_bf16_rne(v[jj] * sc));
}

__device__ __forceinline__ f32x2 exp2v(f32x2 v) {
    f32x2 r; r[0] = EXP2F(v[0]); r[1] = EXP2F(v[1]); return r;
}
__device__ __forceinline__ f32x2 rcpv(f32x2 v) {
    f32x2 r; r[0] = RCPF(v[0]); r[1] = RCPF(v[1]); return r;
}
// Two cells on PRE-SCALED gates (is,fs,os scaled -log2e; gs scaled +2log2e).
__device__ __forceinline__ f32x2 cell2(const f32x4 a0, const f32x4 a1, f32x2* c) {
    f32x2 is = {a0[0], a1[0]}, fs = {a0[1], a1[1]};
    f32x2 gs = {a0[2], a1[2]}, os = {a0[3], a1[3]};
    const f32x2 pf = exp2v(fs);
    const f32x2 fg = rcpv(1.0f + pf);
    const f32x2 pi = exp2v(is);
    const f32x2 e2 = exp2v(gs);
    const f32x2 z  = (e2 - 1.0f) * rcpv((1.0f + pi) * (1.0f + e2));
    *c = fg * (*c) + z;
    const f32x2 po  = exp2v(os);
    const f32x2 e2c = exp2v((*c) * SC_G);
    return (e2c - 1.0f) * rcpv((1.0f + po) * (1.0f + e2c));
}

__device__ __forceinline__ int imin2(int a, int b) { return a < b ? a : b; }
__device__ __forceinline__ int min4of(const int* f) {
    const int4 v = *(const int4*)f;
    return imin2(imin2(v.x, v.y), imin2(v.z, v.w));
}
__device__ __forceinline__ int min8of(const int* f) {
    const int4 a = *(const int4*)f;
    const int4 b = *(const int4*)(f + 4);
    return imin2(imin2(imin2(a.x, a.y), imin2(a.z, a.w)),
                 imin2(imin2(b.x, b.y), imin2(b.z, b.w)));
}

__global__ __launch_bounds__(768, 6)
void lstm_2b_kernel(const float* __restrict__ x,
                    const float* __restrict__ Wih0, const float* __restrict__ Whh0,
                    const float* __restrict__ bih0, const float* __restrict__ bhh0,
                    const float* __restrict__ Wih1, const float* __restrict__ Whh1,
                    const float* __restrict__ bih1, const float* __restrict__ bhh1,
                    const float* __restrict__ Wfc,  const float* __restrict__ bfc,
                    float* __restrict__ out)
{
    __shared__ float xbuf[NB][XP];                   // 16.5 KB
    __shared__ unsigned short h0r[8][RR][64];        // 16 KB ring, slot t&7
    __shared__ unsigned short h1r[2][RR][64];        // 4 KB ring, slot t&1
    __shared__ float h1fin[HH][RR + 1];              // 4.25 KB
    __shared__ __align__(16) int f0[4];              // L0 wave progress flags
    __shared__ __align__(16) int f1[8];              // L1 wave progress flags

    const int tid  = threadIdx.x;
    const int wv   = tid >> 6;       // 0..11: 0-3 L0 waves, 4-11 L1 waves
    const int lane = tid & 63;
    const int m    = lane & 15;      // frag col 0..15; real batch = m (m<8 only)
    const int q    = lane >> 4;      // C-frag unit_local; A/B k-quad
    const int m7   = m & 7;
    const int b0   = blockIdx.x * NB;
    const bool isL0 = (wv < 4);

    // ---- stage x (coalesced float4), 8 real batches ----
    for (int i = tid; i < NB * TT / 4; i += 768) {
        const int b  = i >> 7;            // TT/4 = 128
        const int t4 = i & 127;
        *(float4*)&xbuf[b][t4 * 4] = *(const float4*)&x[(size_t)(b0 + b) * TT + t4 * 4];
    }
    // ---- zero rings (h(-1) served by zeroed slots) + flags ----
    for (int i = tid; i < 8 * RR * 64; i += 768) (&h0r[0][0][0])[i] = 0;
    for (int i = tid; i < 2 * RR * 64; i += 768) (&h1r[0][0][0])[i] = 0;
    if (tid < 4) f0[tid] = -1;
    else if (tid < 12) f1[tid - 4] = -1;

    // ---- per-lane read offsets (shorts within one slot = RR*64 = 1024) ----
    int roff[2];
#pragma unroll
    for (int kt = 0; kt < 2; ++kt)
        roff[kt] = m * 64 + (((4 * kt + q) ^ m7) * 8);

    const int gate_m = m & 3;
    const float scA  = (gate_m == 2) ? SC_G : SC_IFO;
    unsigned short* const H0 = &h0r[0][0][0];
    unsigned short* const H1 = &h1r[0][0][0];

    __syncthreads();     // the ONLY barrier before the epilogue

    if (isL0) {
        // ===== L0 waves: units [16w,16w+16), 4 unit-major tiles, 8 MFMA =====
        const int w = wv;
        bf16x8 Ah[4][2];                    // [tau][kt] of Whh0 (single-term)
        f32x4 bb0s[4], wx0s[4];
        int woff[4];
#pragma unroll
        for (int tau = 0; tau < 4; ++tau) {
            const int rowA = 64 * gate_m + 16 * w + 4 * tau + (m >> 2);
#pragma unroll
            for (int kt = 0; kt < 2; ++kt)
                build_frag_scaled(&Whh0[rowA * HH + kt * 32 + q * 8], scA, Ah[tau][kt]);
#pragma unroll
            for (int r = 0; r < 4; ++r) {
                const int row = 64 * r + 16 * w + 4 * tau + q;
                const float sc = (r == 2) ? SC_G : SC_IFO;
                bb0s[tau][r] = (bih0[row] + bhh0[row]) * sc;
                wx0s[tau][r] = Wih0[row] * sc;
            }
            const int u = 16 * w + 4 * tau + q;
            woff[tau] = m * 64 + (((u >> 3) ^ m7) * 8) + (u & 7);
        }

        f32x2 cA = {0.f, 0.f}, cB = {0.f, 0.f};

#pragma unroll 1
        for (int t = 0; t < TT; ++t) {
            // ---- wait for h0(t-1) complete (all 4 L0 waves) ----
            while (min4of(f0) < t - 1) {
                asm volatile("" ::: "memory");
                __builtin_amdgcn_s_sleep(1);
            }
            asm volatile("" ::: "memory");

            const int rs = ((t - 1) & 7) * (RR * 64);
            bf16x8 h0[2];
            h0[0] = *(const bf16x8*)(H0 + rs + roff[0]);
            h0[1] = *(const bf16x8*)(H0 + rs + roff[1]);
            const float xv = xbuf[m & 7][t];     // lanes m>=8 duplicate batch m-8

            f32x4 a[4];
#pragma unroll
            for (int tau = 0; tau < 4; ++tau) {
                f32x4 p;
#pragma unroll
                for (int r = 0; r < 4; ++r)
                    p[r] = __builtin_fmaf(xv, wx0s[tau][r], bb0s[tau][r]);
                f32x4 z = {0.f, 0.f, 0.f, 0.f};
                p = MFMA(Ah[tau][0], h0[0], p);
                z = MFMA(Ah[tau][1], h0[1], z);
                a[tau] = p + z;
            }

            // ---- back-pressure: slot t&7 (h0(t-8)) fully consumed by L1 ----
            while (min8of(f1) < t - 8) {
                asm volatile("" ::: "memory");
                __builtin_amdgcn_s_sleep(1);
            }
            asm volatile("" ::: "memory");

            const f32x2 hv0 = cell2(a[0], a[1], &cA);
            const f32x2 hv1 = cell2(a[2], a[3], &cB);

            const int ws = (t & 7) * (RR * 64);
            H0[ws + woff[0]] = f32_to_bf16_rne(hv0[0]);
            H0[ws + woff[1]] = f32_to_bf16_rne(hv0[1]);
            H0[ws + woff[2]] = f32_to_bf16_rne(hv1[0]);
            H0[ws + woff[3]] = f32_to_bf16_rne(hv1[1]);

            asm volatile("s_waitcnt lgkmcnt(0)" ::: "memory");
            if (lane == 0) *(volatile int*)&f0[w] = t;
        }
    } else {
        // ===== L1 waves: units [8u,8u+8), 2 tiles, 8 MFMA =====
        const int uW = wv - 4;
        bf16x8 Ah[2][4];     // [tau][kt]: kt0-1 Wih1 (eats h0), kt2-3 Whh1 (eats h1)
        f32x4 bb1s[2];
        int woff[2], uu[2];
#pragma unroll
        for (int tau = 0; tau < 2; ++tau) {
            const int rowA = 64 * gate_m + 8 * uW + 4 * tau + (m >> 2);
#pragma unroll
            for (int kt = 0; kt < 2; ++kt)
                build_frag_scaled(&Wih1[rowA * HH + kt * 32 + q * 8], scA, Ah[tau][kt]);
#pragma unroll
            for (int kt = 0; kt < 2; ++kt)
                build_frag_scaled(&Whh1[rowA * HH + kt * 32 + q * 8], scA, Ah[tau][2 + kt]);
#pragma unroll
            for (int r = 0; r < 4; ++r) {
                const int row = 64 * r + 8 * uW + 4 * tau + q;
                const float sc = (r == 2) ? SC_G : SC_IFO;
                bb1s[tau][r] = (bih1[row] + bhh1[row]) * sc;
            }
            const int u = 8 * uW + 4 * tau + q;
            uu[tau]   = u;
            woff[tau] = m * 64 + (((u >> 3) ^ m7) * 8) + (u & 7);
        }

        f32x2 c1 = {0.f, 0.f};

#pragma unroll 1
        for (int t = 0; t < TT; ++t) {
            // ---- wait for h0(t) (all 4 L0 waves) ----
            while (min4of(f0) < t) {
                asm volatile("" ::: "memory");
                __builtin_amdgcn_s_sleep(1);
            }
            asm volatile("" ::: "memory");
            const int rs0 = (t & 7) * (RR * 64);
            bf16x8 h0[2];
            h0[0] = *(const bf16x8*)(H0 + rs0 + roff[0]);
            h0[1] = *(const bf16x8*)(H0 + rs0 + roff[1]);

            // ---- wait for h1(t-1) (all 8 L1 waves) ----
            while (min8of(f1) < t - 1) {
                asm volatile("" ::: "memory");
                __builtin_amdgcn_s_sleep(1);
            }
            asm volatile("" ::: "memory");
            const int rs1 = ((t - 1) & 1) * (RR * 64);
            bf16x8 h1[2];
            h1[0] = *(const bf16x8*)(H1 + rs1 + roff[0]);
            h1[1] = *(const bf16x8*)(H1 + rs1 + roff[1]);

            f32x4 a[2];
#pragma unroll
            for (int tau = 0; tau < 2; ++tau) {
                f32x4 p = bb1s[tau];
                f32x4 s = {0.f, 0.f, 0.f, 0.f};
                p = MFMA(Ah[tau][0], h0[0], p);        // Wih1 . h0(t)
                p = MFMA(Ah[tau][1], h0[1], p);
                s = MFMA(Ah[tau][2], h1[0], s);        // Whh1 . h1(t-1)
                s = MFMA(Ah[tau][3], h1[1], s);
                a[tau] = p + s;
            }

            const f32x2 hv = cell2(a[0], a[1], &c1);
            if (t == TT - 1) {                  // exact fp32 h1(T-1) for FC
                h1fin[uu[0]][m] = hv[0];
                h1fin[uu[1]][m] = hv[1];
            }
            const int ws = (t & 1) * (RR * 64);
            H1[ws + woff[0]] = f32_to_bf16_rne(hv[0]);
            H1[ws + woff[1]] = f32_to_bf16_rne(hv[1]);

            asm volatile("s_waitcnt lgkmcnt(0)" ::: "memory");
            if (lane == 0) *(volatile int*)&f1[uW] = t;
        }
    }

    __syncthreads();

    // ---- FC epilogue: out[b] = h1(T-1)[b] . Wfc + bfc (8 real batches) ----
    if (tid < NB) {
        float sacc = bfc[0];
#pragma unroll
        for (int u = 0; u < HH; ++u) sacc = fmaf(h1fin[u][tid], Wfc[u], sacc);
        out[b0 + tid] = sacc;
    }
}

extern "C" void kernel_launch(void* const* d_in, const int* in_sizes, int n_in,
                              void* d_out, int out_size, void* d_ws, size_t ws_size,
                              hipStream_t stream) {
    const float* x    = (const float*)d_in[0];
    const float* Wih0 = (const float*)d_in[1];
    const float* Whh0 = (const float*)d_in[2];
    const float* bih0 = (const float*)d_in[3];
    const float* bhh0 = (const float*)d_in[4];
    const float* Wih1 = (const float*)d_in[5];
    const float* Whh1 = (const float*)d_in[6];
    const float* bih1 = (const float*)d_in[7];
    const float* bhh1 = (const float*)d_in[8];
    const float* Wfc  = (const float*)d_in[9];
    const float* bfc  = (const float*)d_in[10];

    lstm_2b_kernel<<<dim3(4096 / NB), dim3(768), 0, stream>>>(
        x, Wih0, Whh0, bih0, bhh0, Wih1, Whh1, bih1, bhh1, Wfc, bfc, (float*)d_out);
}

// Round 17
// 911.517 us; speedup vs baseline: 1.5010x; 1.5010x over previous
//
#include <hip/hip_runtime.h>

// LSTMForecaster: B=4096, T=512, D=1, H=64, 2 layers + FC(64->1).
// R18 = R17 with the spill fixed: __launch_bounds__(768,3) (R16's bound).
//   R17 evidence: occupancy doubled (62%) as intended, but launch_bounds(768,6)
//   capped VGPR at ~85 and the allocator spilled weight frags to scratch
//   (VGPR 68->40, FETCH 5->33MB, WRITE 16KB->34MB, 67MB spill = the 1.4ms).
//   launch_bounds only constrains the ALLOCATOR; HW co-residency follows
//   actual usage: 68 VGPR x 6 waves/SIMD = 408 <= 512, 2 x 41KB LDS <= 160KB,
//   24 <= 32 waves -> two unconstrained R16 blocks fit per CU.
//   This kernel: R16 codegen (launch_bounds(768,3), 68 VGPR) + NB=8, grid 512.
//   Two co-resident blocks on disjoint batches fill each other's dependency
//   stalls (R16 step = 2311 cyc with only ~1050 issue; spin/stall becomes the
//   other block's issue window; step-pair issue ~2100 cyc).
//   Lanes m>=8 deterministically duplicate batch m-8 (same x, zero init) --
//   garbage-free, column-isolated, outputs read only m<8.
//   Math byte-identical to R16 (absmax 6.1e-5): single-term bf16 W, bf16 h,
//   exp2-folded scales, packed cells, free-running flag sync.

#define TT 512
#define HH 64
#define NB 8          // batches per block
#define RR 16         // ring rows (m=0..15 lanes all have a legal row)
#define XP 516

typedef __bf16 bf16_t;
typedef bf16_t bf16x8 __attribute__((ext_vector_type(8)));
typedef float  f32x4  __attribute__((ext_vector_type(4)));
typedef float  f32x2  __attribute__((ext_vector_type(2)));

#define MFMA(A, B, C) __builtin_amdgcn_mfma_f32_16x16x32_bf16((A), (B), (C), 0, 0, 0)
#define RCPF(x) __builtin_amdgcn_rcpf(x)

#if __has_builtin(__builtin_amdgcn_exp2f)
#define EXP2F(x) __builtin_amdgcn_exp2f(x)
#else
__device__ __forceinline__ float EXP2F(float x) {
    float r;
    asm volatile("v_exp_f32 %0, %1" : "=v"(r) : "v"(x));
    return r;
}
#endif

#define SC_IFO (-1.4426950408889634f)   // -log2(e)
#define SC_G   ( 2.8853900817779268f)   // +2*log2(e)

__device__ __forceinline__ unsigned short f32_to_bf16_rne(float f) {
    unsigned int u = __builtin_bit_cast(unsigned int, f);
    unsigned int r = u + 0x7fffu + ((u >> 16) & 1u);
    return (unsigned short)(r >> 16);
}
__device__ __forceinline__ bf16_t bits_to_bf16(unsigned short u) {
    return __builtin_bit_cast(bf16_t, u);
}
// single-term weight frag with per-row scale folded in (RNE)
__device__ __forceinline__ void build_frag_scaled(const float* __restrict__ p, float sc,
                                                  bf16x8& w) {
    const float4 a = *(const float4*)p;
    const float4 b = *(const float4*)(p + 4);
    float v[8] = {a.x, a.y, a.z, a.w, b.x, b.y, b.z, b.w};
#pragma unroll
    for (int jj = 0; jj < 8; ++jj)
        w[jj] = bits_to_bf16(f32_to_bf16_rne(v[jj] * sc));
}

__device__ __forceinline__ f32x2 exp2v(f32x2 v) {
    f32x2 r; r[0] = EXP2F(v[0]); r[1] = EXP2F(v[1]); return r;
}
__device__ __forceinline__ f32x2 rcpv(f32x2 v) {
    f32x2 r; r[0] = RCPF(v[0]); r[1] = RCPF(v[1]); return r;
}
// Two cells on PRE-SCALED gates (is,fs,os scaled -log2e; gs scaled +2log2e).
__device__ __forceinline__ f32x2 cell2(const f32x4 a0, const f32x4 a1, f32x2* c) {
    f32x2 is = {a0[0], a1[0]}, fs = {a0[1], a1[1]};
    f32x2 gs = {a0[2], a1[2]}, os = {a0[3], a1[3]};
    const f32x2 pf = exp2v(fs);
    const f32x2 fg = rcpv(1.0f + pf);
    const f32x2 pi = exp2v(is);
    const f32x2 e2 = exp2v(gs);
    const f32x2 z  = (e2 - 1.0f) * rcpv((1.0f + pi) * (1.0f + e2));
    *c = fg * (*c) + z;
    const f32x2 po  = exp2v(os);
    const f32x2 e2c = exp2v((*c) * SC_G);
    return (e2c - 1.0f) * rcpv((1.0f + po) * (1.0f + e2c));
}

__device__ __forceinline__ int imin2(int a, int b) { return a < b ? a : b; }
__device__ __forceinline__ int min4of(const int* f) {
    const int4 v = *(const int4*)f;
    return imin2(imin2(v.x, v.y), imin2(v.z, v.w));
}
__device__ __forceinline__ int min8of(const int* f) {
    const int4 a = *(const int4*)f;
    const int4 b = *(const int4*)(f + 4);
    return imin2(imin2(imin2(a.x, a.y), imin2(a.z, a.w)),
                 imin2(imin2(b.x, b.y), imin2(b.z, b.w)));
}

__global__ __launch_bounds__(768, 3)
void lstm_2b3_kernel(const float* __restrict__ x,
                     const float* __restrict__ Wih0, const float* __restrict__ Whh0,
                     const float* __restrict__ bih0, const float* __restrict__ bhh0,
                     const float* __restrict__ Wih1, const float* __restrict__ Whh1,
                     const float* __restrict__ bih1, const float* __restrict__ bhh1,
                     const float* __restrict__ Wfc,  const float* __restrict__ bfc,
                     float* __restrict__ out)
{
    __shared__ float xbuf[NB][XP];                   // 16.5 KB
    __shared__ unsigned short h0r[8][RR][64];        // 16 KB ring, slot t&7
    __shared__ unsigned short h1r[2][RR][64];        // 4 KB ring, slot t&1
    __shared__ float h1fin[HH][RR + 1];              // 4.25 KB
    __shared__ __align__(16) int f0[4];              // L0 wave progress flags
    __shared__ __align__(16) int f1[8];              // L1 wave progress flags

    const int tid  = threadIdx.x;
    const int wv   = tid >> 6;       // 0..11: 0-3 L0 waves, 4-11 L1 waves
    const int lane = tid & 63;
    const int m    = lane & 15;      // frag col 0..15; real batch = m (m<8 only)
    const int q    = lane >> 4;      // C-frag unit_local; A/B k-quad
    const int m7   = m & 7;
    const int b0   = blockIdx.x * NB;
    const bool isL0 = (wv < 4);

    // ---- stage x (coalesced float4), 8 real batches ----
    for (int i = tid; i < NB * TT / 4; i += 768) {
        const int b  = i >> 7;            // TT/4 = 128
        const int t4 = i & 127;
        *(float4*)&xbuf[b][t4 * 4] = *(const float4*)&x[(size_t)(b0 + b) * TT + t4 * 4];
    }
    // ---- zero rings (h(-1) served by zeroed slots) + flags ----
    for (int i = tid; i < 8 * RR * 64; i += 768) (&h0r[0][0][0])[i] = 0;
    for (int i = tid; i < 2 * RR * 64; i += 768) (&h1r[0][0][0])[i] = 0;
    if (tid < 4) f0[tid] = -1;
    else if (tid < 12) f1[tid - 4] = -1;

    // ---- per-lane read offsets (shorts within one slot = RR*64 = 1024) ----
    int roff[2];
#pragma unroll
    for (int kt = 0; kt < 2; ++kt)
        roff[kt] = m * 64 + (((4 * kt + q) ^ m7) * 8);

    const int gate_m = m & 3;
    const float scA  = (gate_m == 2) ? SC_G : SC_IFO;
    unsigned short* const H0 = &h0r[0][0][0];
    unsigned short* const H1 = &h1r[0][0][0];

    __syncthreads();     // the ONLY barrier before the epilogue

    if (isL0) {
        // ===== L0 waves: units [16w,16w+16), 4 unit-major tiles, 8 MFMA =====
        const int w = wv;
        bf16x8 Ah[4][2];                    // [tau][kt] of Whh0 (single-term)
        f32x4 bb0s[4], wx0s[4];
        int woff[4];
#pragma unroll
        for (int tau = 0; tau < 4; ++tau) {
            const int rowA = 64 * gate_m + 16 * w + 4 * tau + (m >> 2);
#pragma unroll
            for (int kt = 0; kt < 2; ++kt)
                build_frag_scaled(&Whh0[rowA * HH + kt * 32 + q * 8], scA, Ah[tau][kt]);
#pragma unroll
            for (int r = 0; r < 4; ++r) {
                const int row = 64 * r + 16 * w + 4 * tau + q;
                const float sc = (r == 2) ? SC_G : SC_IFO;
                bb0s[tau][r] = (bih0[row] + bhh0[row]) * sc;
                wx0s[tau][r] = Wih0[row] * sc;
            }
            const int u = 16 * w + 4 * tau + q;
            woff[tau] = m * 64 + (((u >> 3) ^ m7) * 8) + (u & 7);
        }

        f32x2 cA = {0.f, 0.f}, cB = {0.f, 0.f};

#pragma unroll 1
        for (int t = 0; t < TT; ++t) {
            // ---- wait for h0(t-1) complete (all 4 L0 waves) ----
            while (min4of(f0) < t - 1) {
                asm volatile("" ::: "memory");
                __builtin_amdgcn_s_sleep(1);
            }
            asm volatile("" ::: "memory");

            const int rs = ((t - 1) & 7) * (RR * 64);
            bf16x8 h0[2];
            h0[0] = *(const bf16x8*)(H0 + rs + roff[0]);
            h0[1] = *(const bf16x8*)(H0 + rs + roff[1]);
            const float xv = xbuf[m & 7][t];     // lanes m>=8 duplicate batch m-8

            f32x4 a[4];
#pragma unroll
            for (int tau = 0; tau < 4; ++tau) {
                f32x4 p;
#pragma unroll
                for (int r = 0; r < 4; ++r)
                    p[r] = __builtin_fmaf(xv, wx0s[tau][r], bb0s[tau][r]);
                f32x4 z = {0.f, 0.f, 0.f, 0.f};
                p = MFMA(Ah[tau][0], h0[0], p);
                z = MFMA(Ah[tau][1], h0[1], z);
                a[tau] = p + z;
            }

            // ---- back-pressure: slot t&7 (h0(t-8)) fully consumed by L1 ----
            while (min8of(f1) < t - 8) {
                asm volatile("" ::: "memory");
                __builtin_amdgcn_s_sleep(1);
            }
            asm volatile("" ::: "memory");

            const f32x2 hv0 = cell2(a[0], a[1], &cA);
            const f32x2 hv1 = cell2(a[2], a[3], &cB);

            const int ws = (t & 7) * (RR * 64);
            H0[ws + woff[0]] = f32_to_bf16_rne(hv0[0]);
            H0[ws + woff[1]] = f32_to_bf16_rne(hv0[1]);
            H0[ws + woff[2]] = f32_to_bf16_rne(hv1[0]);
            H0[ws + woff[3]] = f32_to_bf16_rne(hv1[1]);

            asm volatile("s_waitcnt lgkmcnt(0)" ::: "memory");
            if (lane == 0) *(volatile int*)&f0[w] = t;
        }
    } else {
        // ===== L1 waves: units [8u,8u+8), 2 tiles, 8 MFMA =====
        const int uW = wv - 4;
        bf16x8 Ah[2][4];     // [tau][kt]: kt0-1 Wih1 (eats h0), kt2-3 Whh1 (eats h1)
        f32x4 bb1s[2];
        int woff[2], uu[2];
#pragma unroll
        for (int tau = 0; tau < 2; ++tau) {
            const int rowA = 64 * gate_m + 8 * uW + 4 * tau + (m >> 2);
#pragma unroll
            for (int kt = 0; kt < 2; ++kt)
                build_frag_scaled(&Wih1[rowA * HH + kt * 32 + q * 8], scA, Ah[tau][kt]);
#pragma unroll
            for (int kt = 0; kt < 2; ++kt)
                build_frag_scaled(&Whh1[rowA * HH + kt * 32 + q * 8], scA, Ah[tau][2 + kt]);
#pragma unroll
            for (int r = 0; r < 4; ++r) {
                const int row = 64 * r + 8 * uW + 4 * tau + q;
                const float sc = (r == 2) ? SC_G : SC_IFO;
                bb1s[tau][r] = (bih1[row] + bhh1[row]) * sc;
            }
            const int u = 8 * uW + 4 * tau + q;
            uu[tau]   = u;
            woff[tau] = m * 64 + (((u >> 3) ^ m7) * 8) + (u & 7);
        }

        f32x2 c1 = {0.f, 0.f};

#pragma unroll 1
        for (int t = 0; t < TT; ++t) {
            // ---- wait for h0(t) (all 4 L0 waves) ----
            while (min4of(f0) < t) {
                asm volatile("" ::: "memory");
                __builtin_amdgcn_s_sleep(1);
            }
            asm volatile("" ::: "memory");
            const int rs0 = (t & 7) * (RR * 64);
            bf16x8 h0[2];
            h0[0] = *(const bf16x8*)(H0 + rs0 + roff[0]);
            h0[1] = *(const bf16x8*)(H0 + rs0 + roff[1]);

            // ---- wait for h1(t-1) (all 8 L1 waves) ----
            while (min8of(f1) < t - 1) {
                asm volatile("" ::: "memory");
                __builtin_amdgcn_s_sleep(1);
            }
            asm volatile("" ::: "memory");
            const int rs1 = ((t - 1) & 1) * (RR * 64);
            bf16x8 h1[2];
            h1[0] = *(const bf16x8*)(H1 + rs1 + roff[0]);
            h1[1] = *(const bf16x8*)(H1 + rs1 + roff[1]);

            f32x4 a[2];
#pragma unroll
            for (int tau = 0; tau < 2; ++tau) {
                f32x4 p = bb1s[tau];
                f32x4 s = {0.f, 0.f, 0.f, 0.f};
                p = MFMA(Ah[tau][0], h0[0], p);        // Wih1 . h0(t)
                p = MFMA(Ah[tau][1], h0[1], p);
                s = MFMA(Ah[tau][2], h1[0], s);        // Whh1 . h1(t-1)
                s = MFMA(Ah[tau][3], h1[1], s);
                a[tau] = p + s;
            }

            const f32x2 hv = cell2(a[0], a[1], &c1);
            if (t == TT - 1) {                  // exact fp32 h1(T-1) for FC
                h1fin[uu[0]][m] = hv[0];
                h1fin[uu[1]][m] = hv[1];
            }
            const int ws = (t & 1) * (RR * 64);
            H1[ws + woff[0]] = f32_to_bf16_rne(hv[0]);
            H1[ws + woff[1]] = f32_to_bf16_rne(hv[1]);

            asm volatile("s_waitcnt lgkmcnt(0)" ::: "memory");
            if (lane == 0) *(volatile int*)&f1[uW] = t;
        }
    }

    __syncthreads();

    // ---- FC epilogue: out[b] = h1(T-1)[b] . Wfc + bfc (8 real batches) ----
    if (tid < NB) {
        float sacc = bfc[0];
#pragma unroll
        for (int u = 0; u < HH; ++u) sacc = fmaf(h1fin[u][tid], Wfc[u], sacc);
        out[b0 + tid] = sacc;
    }
}

extern "C" void kernel_launch(void* const* d_in, const int* in_sizes, int n_in,
                              void* d_out, int out_size, void* d_ws, size_t ws_size,
                              hipStream_t stream) {
    const float* x    = (const float*)d_in[0];
    const float* Wih0 = (const float*)d_in[1];
    const float* Whh0 = (const float*)d_in[2];
    const float* bih0 = (const float*)d_in[3];
    const float* bhh0 = (const float*)d_in[4];
    const float* Wih1 = (const float*)d_in[5];
    const float* Whh1 = (const float*)d_in[6];
    const float* bih1 = (const float*)d_in[7];
    const float* bhh1 = (const float*)d_in[8];
    const float* Wfc  = (const float*)d_in[9];
    const float* bfc  = (const float*)d_in[10];

    lstm_2b3_kernel<<<dim3(4096 / NB), dim3(768), 0, stream>>>(
        x, Wih0, Whh0, bih0, bhh0, Wih1, Whh1, bih1, bhh1, Wfc, bfc, (float*)d_out);
}

// Round 18
// 839.199 us; speedup vs baseline: 1.6303x; 1.0862x over previous
//
#include <hip/hip_runtime.h>

// LSTMForecaster: B=4096, T=512, D=1, H=64, 2 layers + FC(64->1).
// R19: two co-resident blocks, sized UNDER the VGPR-tier wave cap.
//   R18 failed co-residency: 68 VGPR -> 128-reg allocation tier (m69: waves
//   halve at vgpr={64,128,256}) -> 16-wave/CU cap -> two 12-wave blocks (24)
//   don't fit; occupancy stayed 35% and the grid serialized (912us ~ 2x493).
//   Fix: 8-wave blocks (512 thr), NB=8, grid 512. Two blocks = 16 waves =
//   exactly the 4-waves/SIMD cap at the 128-tier. Roles per block:
//   4 L0 waves x 16 units (8 MFMA + 2 cell2, same as R16 L0) and
//   4 L1 waves x 16 units (16 MFMA + 2 cell2). launch_bounds(512,4) caps
//   VGPR at 128 (L1 needs ~110 -> no spill, unlike R17's 85-cap disaster).
//   Each SIMD hosts 1 L0 + 1 L1 from each of two independent blocks: one
//   block's dependency stalls are the other's issue window (m114 co-issue).
//   MFMA cols 8-15 duplicate batch m-8 (deterministic, column-isolated).
//   Math byte-identical to R16 (absmax 6.1e-5): single-term bf16 W, bf16 h,
//   exp2-folded scales, packed cells, free-running flag sync, rings 8/2.

#define TT 512
#define HH 64
#define NB 8          // real batches per block
#define RR 16         // ring rows (frag cols 0..15 all have a legal row)
#define XP 516

typedef __bf16 bf16_t;
typedef bf16_t bf16x8 __attribute__((ext_vector_type(8)));
typedef float  f32x4  __attribute__((ext_vector_type(4)));
typedef float  f32x2  __attribute__((ext_vector_type(2)));

#define MFMA(A, B, C) __builtin_amdgcn_mfma_f32_16x16x32_bf16((A), (B), (C), 0, 0, 0)
#define RCPF(x) __builtin_amdgcn_rcpf(x)

#if __has_builtin(__builtin_amdgcn_exp2f)
#define EXP2F(x) __builtin_amdgcn_exp2f(x)
#else
__device__ __forceinline__ float EXP2F(float x) {
    float r;
    asm volatile("v_exp_f32 %0, %1" : "=v"(r) : "v"(x));
    return r;
}
#endif

#define SC_IFO (-1.4426950408889634f)   // -log2(e)
#define SC_G   ( 2.8853900817779268f)   // +2*log2(e)

__device__ __forceinline__ unsigned short f32_to_bf16_rne(float f) {
    unsigned int u = __builtin_bit_cast(unsigned int, f);
    unsigned int r = u + 0x7fffu + ((u >> 16) & 1u);
    return (unsigned short)(r >> 16);
}
__device__ __forceinline__ bf16_t bits_to_bf16(unsigned short u) {
    return __builtin_bit_cast(bf16_t, u);
}
// single-term weight frag with per-row scale folded in (RNE)
__device__ __forceinline__ void build_frag_scaled(const float* __restrict__ p, float sc,
                                                  bf16x8& w) {
    const float4 a = *(const float4*)p;
    const float4 b = *(const float4*)(p + 4);
    float v[8] = {a.x, a.y, a.z, a.w, b.x, b.y, b.z, b.w};
#pragma unroll
    for (int jj = 0; jj < 8; ++jj)
        w[jj] = bits_to_bf16(f32_to_bf16_rne(v[jj] * sc));
}

__device__ __forceinline__ f32x2 exp2v(f32x2 v) {
    f32x2 r; r[0] = EXP2F(v[0]); r[1] = EXP2F(v[1]); return r;
}
__device__ __forceinline__ f32x2 rcpv(f32x2 v) {
    f32x2 r; r[0] = RCPF(v[0]); r[1] = RCPF(v[1]); return r;
}
// Two cells on PRE-SCALED gates (is,fs,os scaled -log2e; gs scaled +2log2e).
__device__ __forceinline__ f32x2 cell2(const f32x4 a0, const f32x4 a1, f32x2* c) {
    f32x2 is = {a0[0], a1[0]}, fs = {a0[1], a1[1]};
    f32x2 gs = {a0[2], a1[2]}, os = {a0[3], a1[3]};
    const f32x2 pf = exp2v(fs);
    const f32x2 fg = rcpv(1.0f + pf);
    const f32x2 pi = exp2v(is);
    const f32x2 e2 = exp2v(gs);
    const f32x2 z  = (e2 - 1.0f) * rcpv((1.0f + pi) * (1.0f + e2));
    *c = fg * (*c) + z;
    const f32x2 po  = exp2v(os);
    const f32x2 e2c = exp2v((*c) * SC_G);
    return (e2c - 1.0f) * rcpv((1.0f + po) * (1.0f + e2c));
}

__device__ __forceinline__ int imin2(int a, int b) { return a < b ? a : b; }
__device__ __forceinline__ int min4of(const int* f) {
    const int4 v = *(const int4*)f;
    return imin2(imin2(v.x, v.y), imin2(v.z, v.w));
}

__global__ __launch_bounds__(512, 4)
void lstm_cr_kernel(const float* __restrict__ x,
                    const float* __restrict__ Wih0, const float* __restrict__ Whh0,
                    const float* __restrict__ bih0, const float* __restrict__ bhh0,
                    const float* __restrict__ Wih1, const float* __restrict__ Whh1,
                    const float* __restrict__ bih1, const float* __restrict__ bhh1,
                    const float* __restrict__ Wfc,  const float* __restrict__ bfc,
                    float* __restrict__ out)
{
    __shared__ float xbuf[NB][XP];                   // 16.5 KB
    __shared__ unsigned short h0r[8][RR][64];        // 16 KB ring, slot t&7
    __shared__ unsigned short h1r[2][RR][64];        // 4 KB ring, slot t&1
    __shared__ float h1fin[HH][RR + 1];              // 4.25 KB
    __shared__ __align__(16) int f0[4];              // L0 wave progress flags
    __shared__ __align__(16) int f1[4];              // L1 wave progress flags

    const int tid  = threadIdx.x;
    const int wv   = tid >> 6;       // 0..7: 0-3 L0 waves, 4-7 L1 waves
    const int lane = tid & 63;
    const int m    = lane & 15;      // frag col 0..15; real batch = m&7
    const int q    = lane >> 4;      // C-frag unit_local; A/B k-quad
    const int m7   = m & 7;
    const int b0   = blockIdx.x * NB;
    const bool isL0 = (wv < 4);

    // ---- stage x (coalesced float4), 8 real batches ----
    for (int i = tid; i < NB * TT / 4; i += 512) {
        const int b  = i >> 7;            // TT/4 = 128
        const int t4 = i & 127;
        *(float4*)&xbuf[b][t4 * 4] = *(const float4*)&x[(size_t)(b0 + b) * TT + t4 * 4];
    }
    // ---- zero rings (h(-1) served by zeroed slots) + flags ----
    for (int i = tid; i < 8 * RR * 64; i += 512) (&h0r[0][0][0])[i] = 0;
    for (int i = tid; i < 2 * RR * 64; i += 512) (&h1r[0][0][0])[i] = 0;
    if (tid < 4) f0[tid] = -1;
    else if (tid < 8) f1[tid - 4] = -1;

    // ---- per-lane read offsets (shorts within one slot = RR*64 = 1024) ----
    int roff[2];
#pragma unroll
    for (int kt = 0; kt < 2; ++kt)
        roff[kt] = m * 64 + (((4 * kt + q) ^ m7) * 8);

    const int gate_m = m & 3;
    const float scA  = (gate_m == 2) ? SC_G : SC_IFO;
    unsigned short* const H0 = &h0r[0][0][0];
    unsigned short* const H1 = &h1r[0][0][0];

    __syncthreads();     // the ONLY barrier before the epilogue

    if (isL0) {
        // ===== L0 waves: units [16w,16w+16), 4 unit-major tiles, 8 MFMA =====
        const int w = wv;
        bf16x8 Ah[4][2];                    // [tau][kt] of Whh0 (single-term)
        f32x4 bb0s[4], wx0s[4];
        int woff[4];
#pragma unroll
        for (int tau = 0; tau < 4; ++tau) {
            const int rowA = 64 * gate_m + 16 * w + 4 * tau + (m >> 2);
#pragma unroll
            for (int kt = 0; kt < 2; ++kt)
                build_frag_scaled(&Whh0[rowA * HH + kt * 32 + q * 8], scA, Ah[tau][kt]);
#pragma unroll
            for (int r = 0; r < 4; ++r) {
                const int row = 64 * r + 16 * w + 4 * tau + q;
                const float sc = (r == 2) ? SC_G : SC_IFO;
                bb0s[tau][r] = (bih0[row] + bhh0[row]) * sc;
                wx0s[tau][r] = Wih0[row] * sc;
            }
            const int u = 16 * w + 4 * tau + q;
            woff[tau] = m * 64 + (((u >> 3) ^ m7) * 8) + (u & 7);
        }

        f32x2 cA = {0.f, 0.f}, cB = {0.f, 0.f};

#pragma unroll 1
        for (int t = 0; t < TT; ++t) {
            // ---- wait for h0(t-1) complete (all 4 L0 waves) ----
            while (min4of(f0) < t - 1) {
                asm volatile("" ::: "memory");
                __builtin_amdgcn_s_sleep(1);
            }
            asm volatile("" ::: "memory");

            const int rs = ((t - 1) & 7) * (RR * 64);
            bf16x8 h0[2];
            h0[0] = *(const bf16x8*)(H0 + rs + roff[0]);
            h0[1] = *(const bf16x8*)(H0 + rs + roff[1]);
            const float xv = xbuf[m & 7][t];     // cols m>=8 duplicate batch m-8

            f32x4 a[4];
#pragma unroll
            for (int tau = 0; tau < 4; ++tau) {
                f32x4 p;
#pragma unroll
                for (int r = 0; r < 4; ++r)
                    p[r] = __builtin_fmaf(xv, wx0s[tau][r], bb0s[tau][r]);
                f32x4 z = {0.f, 0.f, 0.f, 0.f};
                p = MFMA(Ah[tau][0], h0[0], p);
                z = MFMA(Ah[tau][1], h0[1], z);
                a[tau] = p + z;
            }

            // ---- back-pressure: slot t&7 (h0(t-8)) fully consumed by L1 ----
            while (min4of(f1) < t - 8) {
                asm volatile("" ::: "memory");
                __builtin_amdgcn_s_sleep(1);
            }
            asm volatile("" ::: "memory");

            const f32x2 hv0 = cell2(a[0], a[1], &cA);
            const f32x2 hv1 = cell2(a[2], a[3], &cB);

            const int ws = (t & 7) * (RR * 64);
            H0[ws + woff[0]] = f32_to_bf16_rne(hv0[0]);
            H0[ws + woff[1]] = f32_to_bf16_rne(hv0[1]);
            H0[ws + woff[2]] = f32_to_bf16_rne(hv1[0]);
            H0[ws + woff[3]] = f32_to_bf16_rne(hv1[1]);

            asm volatile("s_waitcnt lgkmcnt(0)" ::: "memory");
            if (lane == 0) *(volatile int*)&f0[w] = t;
        }
    } else {
        // ===== L1 waves: units [16u,16u+16), 4 tiles, 16 MFMA =====
        const int uW = wv - 4;
        bf16x8 Ah[4][4];     // [tau][kt]: kt0-1 Wih1 (eats h0), kt2-3 Whh1 (eats h1)
        f32x4 bb1s[4];
        int woff[4], uu[4];
#pragma unroll
        for (int tau = 0; tau < 4; ++tau) {
            const int rowA = 64 * gate_m + 16 * uW + 4 * tau + (m >> 2);
#pragma unroll
            for (int kt = 0; kt < 2; ++kt)
                build_frag_scaled(&Wih1[rowA * HH + kt * 32 + q * 8], scA, Ah[tau][kt]);
#pragma unroll
            for (int kt = 0; kt < 2; ++kt)
                build_frag_scaled(&Whh1[rowA * HH + kt * 32 + q * 8], scA, Ah[tau][2 + kt]);
#pragma unroll
            for (int r = 0; r < 4; ++r) {
                const int row = 64 * r + 16 * uW + 4 * tau + q;
                const float sc = (r == 2) ? SC_G : SC_IFO;
                bb1s[tau][r] = (bih1[row] + bhh1[row]) * sc;
            }
            const int u = 16 * uW + 4 * tau + q;
            uu[tau]   = u;
            woff[tau] = m * 64 + (((u >> 3) ^ m7) * 8) + (u & 7);
        }

        f32x2 c1a = {0.f, 0.f}, c1b = {0.f, 0.f};

#pragma unroll 1
        for (int t = 0; t < TT; ++t) {
            // ---- wait for h0(t) (all 4 L0 waves) ----
            while (min4of(f0) < t) {
                asm volatile("" ::: "memory");
                __builtin_amdgcn_s_sleep(1);
            }
            asm volatile("" ::: "memory");
            const int rs0 = (t & 7) * (RR * 64);
            bf16x8 h0[2];
            h0[0] = *(const bf16x8*)(H0 + rs0 + roff[0]);
            h0[1] = *(const bf16x8*)(H0 + rs0 + roff[1]);

            // ---- wait for h1(t-1) (all 4 L1 waves) ----
            while (min4of(f1) < t - 1) {
                asm volatile("" ::: "memory");
                __builtin_amdgcn_s_sleep(1);
            }
            asm volatile("" ::: "memory");
            const int rs1 = ((t - 1) & 1) * (RR * 64);
            bf16x8 h1[2];
            h1[0] = *(const bf16x8*)(H1 + rs1 + roff[0]);
            h1[1] = *(const bf16x8*)(H1 + rs1 + roff[1]);

            f32x4 a[4];
#pragma unroll
            for (int tau = 0; tau < 4; ++tau) {
                f32x4 p = bb1s[tau];
                f32x4 s = {0.f, 0.f, 0.f, 0.f};
                p = MFMA(Ah[tau][0], h0[0], p);        // Wih1 . h0(t)
                p = MFMA(Ah[tau][1], h0[1], p);
                s = MFMA(Ah[tau][2], h1[0], s);        // Whh1 . h1(t-1)
                s = MFMA(Ah[tau][3], h1[1], s);
                a[tau] = p + s;
            }

            const f32x2 hva = cell2(a[0], a[1], &c1a);
            const f32x2 hvb = cell2(a[2], a[3], &c1b);
            if (t == TT - 1) {                  // exact fp32 h1(T-1) for FC
                h1fin[uu[0]][m] = hva[0];
                h1fin[uu[1]][m] = hva[1];
                h1fin[uu[2]][m] = hvb[0];
                h1fin[uu[3]][m] = hvb[1];
            }
            const int ws = (t & 1) * (RR * 64);
            H1[ws + woff[0]] = f32_to_bf16_rne(hva[0]);
            H1[ws + woff[1]] = f32_to_bf16_rne(hva[1]);
            H1[ws + woff[2]] = f32_to_bf16_rne(hvb[0]);
            H1[ws + woff[3]] = f32_to_bf16_rne(hvb[1]);

            asm volatile("s_waitcnt lgkmcnt(0)" ::: "memory");
            if (lane == 0) *(volatile int*)&f1[uW] = t;
        }
    }

    __syncthreads();

    // ---- FC epilogue: out[b] = h1(T-1)[b] . Wfc + bfc (8 real batches) ----
    if (tid < NB) {
        float sacc = bfc[0];
#pragma unroll
        for (int u = 0; u < HH; ++u) sacc = fmaf(h1fin[u][tid], Wfc[u], sacc);
        out[b0 + tid] = sacc;
    }
}

extern "C" void kernel_launch(void* const* d_in, const int* in_sizes, int n_in,
                              void* d_out, int out_size, void* d_ws, size_t ws_size,
                              hipStream_t stream) {
    const float* x    = (const float*)d_in[0];
    const float* Wih0 = (const float*)d_in[1];
    const float* Whh0 = (const float*)d_in[2];
    const float* bih0 = (const float*)d_in[3];
    const float* bhh0 = (const float*)d_in[4];
    const float* Wih1 = (const float*)d_in[5];
    const float* Whh1 = (const float*)d_in[6];
    const float* bih1 = (const float*)d_in[7];
    const float* bhh1 = (const float*)d_in[8];
    const float* Wfc  = (const float*)d_in[9];
    const float* bfc  = (const float*)d_in[10];

    lstm_cr_kernel<<<dim3(4096 / NB), dim3(512), 0, stream>>>(
        x, Wih0, Whh0, bih0, bhh0, Wih1, Whh1, bih1, bhh1, Wfc, bfc, (float*)d_out);
}

// Round 19
// 516.592 us; speedup vs baseline: 2.6485x; 1.6245x over previous
//
#include <hip/hip_runtime.h>

// LSTMForecaster: B=4096, T=512, D=1, H=64, 2 layers + FC(64->1).
// R20 = R16 (champion, 493us) + critical-chain micro-cuts. Co-residency is
//   structurally closed (R17/R19 spill at the 256/w launch-bounds cap; R18
//   doesn't pack at the 128-VGPR tier). Remaining lever = the per-step serial
//   chain. Cuts:
//   (1) polls drop s_sleep(1): it adds ~64 cyc detect lag per iteration and
//       buys nothing -- the wave already yields inside s_waitcnt on the flag
//       ds_read. L1 has 2 polls on the critical chain.
//   (2) L1 hoists h0-read + h0-MFMAs ABOVE the f1 poll (f0 is pre-satisfied;
//       L0 runs ~8 ahead on the ring) -> f1->publish chain loses ~150 cyc.
//   (3) L0 reads xv before its poll.
//   Everything else byte-identical to R16: 12 waves (4 L0 x 16u, 8 L1 x 8u),
//   single-term bf16 W, bf16 h, exp2-folded scales, packed cells, rings 8/2,
//   free-running monotone flags. absmax 6.1e-5.

#define TT 512
#define HH 64
#define NB 16
#define XP 516

typedef __bf16 bf16_t;
typedef bf16_t bf16x8 __attribute__((ext_vector_type(8)));
typedef float  f32x4  __attribute__((ext_vector_type(4)));
typedef float  f32x2  __attribute__((ext_vector_type(2)));

#define MFMA(A, B, C) __builtin_amdgcn_mfma_f32_16x16x32_bf16((A), (B), (C), 0, 0, 0)
#define RCPF(x) __builtin_amdgcn_rcpf(x)

#if __has_builtin(__builtin_amdgcn_exp2f)
#define EXP2F(x) __builtin_amdgcn_exp2f(x)
#else
__device__ __forceinline__ float EXP2F(float x) {
    float r;
    asm volatile("v_exp_f32 %0, %1" : "=v"(r) : "v"(x));
    return r;
}
#endif

#define SC_IFO (-1.4426950408889634f)   // -log2(e)
#define SC_G   ( 2.8853900817779268f)   // +2*log2(e)

__device__ __forceinline__ unsigned short f32_to_bf16_rne(float f) {
    unsigned int u = __builtin_bit_cast(unsigned int, f);
    unsigned int r = u + 0x7fffu + ((u >> 16) & 1u);
    return (unsigned short)(r >> 16);
}
__device__ __forceinline__ bf16_t bits_to_bf16(unsigned short u) {
    return __builtin_bit_cast(bf16_t, u);
}
// single-term weight frag with per-row scale folded in (RNE)
__device__ __forceinline__ void build_frag_scaled(const float* __restrict__ p, float sc,
                                                  bf16x8& w) {
    const float4 a = *(const float4*)p;
    const float4 b = *(const float4*)(p + 4);
    float v[8] = {a.x, a.y, a.z, a.w, b.x, b.y, b.z, b.w};
#pragma unroll
    for (int jj = 0; jj < 8; ++jj)
        w[jj] = bits_to_bf16(f32_to_bf16_rne(v[jj] * sc));
}

__device__ __forceinline__ f32x2 exp2v(f32x2 v) {
    f32x2 r; r[0] = EXP2F(v[0]); r[1] = EXP2F(v[1]); return r;
}
__device__ __forceinline__ f32x2 rcpv(f32x2 v) {
    f32x2 r; r[0] = RCPF(v[0]); r[1] = RCPF(v[1]); return r;
}
// Two cells on PRE-SCALED gates (is,fs,os scaled -log2e; gs scaled +2log2e).
__device__ __forceinline__ f32x2 cell2(const f32x4 a0, const f32x4 a1, f32x2* c) {
    f32x2 is = {a0[0], a1[0]}, fs = {a0[1], a1[1]};
    f32x2 gs = {a0[2], a1[2]}, os = {a0[3], a1[3]};
    const f32x2 pf = exp2v(fs);
    const f32x2 fg = rcpv(1.0f + pf);
    const f32x2 pi = exp2v(is);
    const f32x2 e2 = exp2v(gs);
    const f32x2 z  = (e2 - 1.0f) * rcpv((1.0f + pi) * (1.0f + e2));
    *c = fg * (*c) + z;
    const f32x2 po  = exp2v(os);
    const f32x2 e2c = exp2v((*c) * SC_G);
    return (e2c - 1.0f) * rcpv((1.0f + po) * (1.0f + e2c));
}

__device__ __forceinline__ int imin2(int a, int b) { return a < b ? a : b; }
__device__ __forceinline__ int min4of(const int* f) {
    const int4 v = *(const int4*)f;
    return imin2(imin2(v.x, v.y), imin2(v.z, v.w));
}
__device__ __forceinline__ int min8of(const int* f) {
    const int4 a = *(const int4*)f;
    const int4 b = *(const int4*)(f + 4);
    return imin2(imin2(imin2(a.x, a.y), imin2(a.z, a.w)),
                 imin2(imin2(b.x, b.y), imin2(b.z, b.w)));
}

__global__ __launch_bounds__(768, 3)
void lstm_fast_kernel(const float* __restrict__ x,
                      const float* __restrict__ Wih0, const float* __restrict__ Whh0,
                      const float* __restrict__ bih0, const float* __restrict__ bhh0,
                      const float* __restrict__ Wih1, const float* __restrict__ Whh1,
                      const float* __restrict__ bih1, const float* __restrict__ bhh1,
                      const float* __restrict__ Wfc,  const float* __restrict__ bfc,
                      float* __restrict__ out)
{
    __shared__ float xbuf[NB][XP];                   // 33 KB
    __shared__ unsigned short h0r[8][NB][64];        // 16 KB ring, slot t&7
    __shared__ unsigned short h1r[2][NB][64];        // 4 KB ring, slot t&1
    __shared__ float h1fin[HH][NB + 1];              // 4.25 KB
    __shared__ __align__(16) int f0[4];              // L0 wave progress flags
    __shared__ __align__(16) int f1[8];              // L1 wave progress flags

    const int tid  = threadIdx.x;
    const int wv   = tid >> 6;       // 0..11: 0-3 L0 waves, 4-11 L1 waves
    const int lane = tid & 63;
    const int m    = lane & 15;      // batch col (B/C frag) & A-frag row-in-tile
    const int q    = lane >> 4;      // C-frag unit_local; A/B k-quad
    const int m7   = m & 7;
    const int b0   = blockIdx.x * NB;
    const bool isL0 = (wv < 4);

    // ---- stage x (coalesced float4) ----
    for (int i = tid; i < NB * TT / 4; i += 768) {
        const int b  = i >> 7;
        const int t4 = i & 127;
        *(float4*)&xbuf[b][t4 * 4] = *(const float4*)&x[(size_t)(b0 + b) * TT + t4 * 4];
    }
    // ---- zero rings (h(-1) served by zeroed slots) + flags ----
    for (int i = tid; i < 8 * NB * 64; i += 768) (&h0r[0][0][0])[i] = 0;
    for (int i = tid; i < 2 * NB * 64; i += 768) (&h1r[0][0][0])[i] = 0;
    if (tid < 4) f0[tid] = -1;
    else if (tid < 12) f1[tid - 4] = -1;

    // ---- per-lane read offsets (shorts within one slot = 1024) ----
    int roff[2];
#pragma unroll
    for (int kt = 0; kt < 2; ++kt)
        roff[kt] = m * 64 + (((4 * kt + q) ^ m7) * 8);

    const int gate_m = m & 3;
    const float scA  = (gate_m == 2) ? SC_G : SC_IFO;
    unsigned short* const H0 = &h0r[0][0][0];
    unsigned short* const H1 = &h1r[0][0][0];

    __syncthreads();     // the ONLY barrier before the epilogue

    if (isL0) {
        // ===== L0 waves: units [16w,16w+16), 4 unit-major tiles, 8 MFMA =====
        const int w = wv;
        bf16x8 Ah[4][2];                    // [tau][kt] of Whh0 (single-term)
        f32x4 bb0s[4], wx0s[4];
        int woff[4];
#pragma unroll
        for (int tau = 0; tau < 4; ++tau) {
            const int rowA = 64 * gate_m + 16 * w + 4 * tau + (m >> 2);
#pragma unroll
            for (int kt = 0; kt < 2; ++kt)
                build_frag_scaled(&Whh0[rowA * HH + kt * 32 + q * 8], scA, Ah[tau][kt]);
#pragma unroll
            for (int r = 0; r < 4; ++r) {
                const int row = 64 * r + 16 * w + 4 * tau + q;
                const float sc = (r == 2) ? SC_G : SC_IFO;
                bb0s[tau][r] = (bih0[row] + bhh0[row]) * sc;
                wx0s[tau][r] = Wih0[row] * sc;
            }
            const int u = 16 * w + 4 * tau + q;
            woff[tau] = m * 64 + (((u >> 3) ^ m7) * 8) + (u & 7);
        }

        f32x2 cA = {0.f, 0.f}, cB = {0.f, 0.f};

#pragma unroll 1
        for (int t = 0; t < TT; ++t) {
            const float xv = xbuf[m][t];     // independent of flags: read early

            // ---- wait for h0(t-1) complete (all 4 L0 waves); no sleep ----
            while (min4of(f0) < t - 1) {
                asm volatile("" ::: "memory");
            }
            asm volatile("" ::: "memory");

            const int rs = ((t - 1) & 7) * (NB * 64);
            bf16x8 h0[2];
            h0[0] = *(const bf16x8*)(H0 + rs + roff[0]);
            h0[1] = *(const bf16x8*)(H0 + rs + roff[1]);

            f32x4 a[4];
#pragma unroll
            for (int tau = 0; tau < 4; ++tau) {
                f32x4 p;
#pragma unroll
                for (int r = 0; r < 4; ++r)
                    p[r] = __builtin_fmaf(xv, wx0s[tau][r], bb0s[tau][r]);
                f32x4 z = {0.f, 0.f, 0.f, 0.f};
                p = MFMA(Ah[tau][0], h0[0], p);
                z = MFMA(Ah[tau][1], h0[1], z);
                a[tau] = p + z;
            }

            // ---- back-pressure: slot t&7 (h0(t-8)) fully consumed by L1 ----
            while (min8of(f1) < t - 8) {
                asm volatile("" ::: "memory");
            }
            asm volatile("" ::: "memory");

            const f32x2 hv0 = cell2(a[0], a[1], &cA);
            const f32x2 hv1 = cell2(a[2], a[3], &cB);

            const int ws = (t & 7) * (NB * 64);
            H0[ws + woff[0]] = f32_to_bf16_rne(hv0[0]);
            H0[ws + woff[1]] = f32_to_bf16_rne(hv0[1]);
            H0[ws + woff[2]] = f32_to_bf16_rne(hv1[0]);
            H0[ws + woff[3]] = f32_to_bf16_rne(hv1[1]);

            asm volatile("s_waitcnt lgkmcnt(0)" ::: "memory");
            if (lane == 0) *(volatile int*)&f0[w] = t;
        }
    } else {
        // ===== L1 waves: units [8u,8u+8), 2 tiles, 8 MFMA =====
        const int uW = wv - 4;
        bf16x8 Ah[2][4];     // [tau][kt]: kt0-1 Wih1 (eats h0), kt2-3 Whh1 (eats h1)
        f32x4 bb1s[2];
        int woff[2], uu[2];
#pragma unroll
        for (int tau = 0; tau < 2; ++tau) {
            const int rowA = 64 * gate_m + 8 * uW + 4 * tau + (m >> 2);
#pragma unroll
            for (int kt = 0; kt < 2; ++kt)
                build_frag_scaled(&Wih1[rowA * HH + kt * 32 + q * 8], scA, Ah[tau][kt]);
#pragma unroll
            for (int kt = 0; kt < 2; ++kt)
                build_frag_scaled(&Whh1[rowA * HH + kt * 32 + q * 8], scA, Ah[tau][2 + kt]);
#pragma unroll
            for (int r = 0; r < 4; ++r) {
                const int row = 64 * r + 8 * uW + 4 * tau + q;
                const float sc = (r == 2) ? SC_G : SC_IFO;
                bb1s[tau][r] = (bih1[row] + bhh1[row]) * sc;
            }
            const int u = 8 * uW + 4 * tau + q;
            uu[tau]   = u;
            woff[tau] = m * 64 + (((u >> 3) ^ m7) * 8) + (u & 7);
        }

        f32x2 c1 = {0.f, 0.f};

#pragma unroll 1
        for (int t = 0; t < TT; ++t) {
            // ---- slack gate: h0(t) ready (L0 runs ~8 ahead; usually instant) ----
            while (min4of(f0) < t) {
                asm volatile("" ::: "memory");
            }
            asm volatile("" ::: "memory");
            const int rs0 = (t & 7) * (NB * 64);
            bf16x8 h0[2];
            h0[0] = *(const bf16x8*)(H0 + rs0 + roff[0]);
            h0[1] = *(const bf16x8*)(H0 + rs0 + roff[1]);

            // ---- h0 burst BEFORE the tight f1 poll (off the critical chain) ----
            f32x4 p[2];
#pragma unroll
            for (int tau = 0; tau < 2; ++tau) {
                f32x4 acc = bb1s[tau];
                acc = MFMA(Ah[tau][0], h0[0], acc);    // Wih1 . h0(t)
                acc = MFMA(Ah[tau][1], h0[1], acc);
                p[tau] = acc;
            }

            // ---- tight: h1(t-1) ready (all 8 L1 waves); no sleep ----
            while (min8of(f1) < t - 1) {
                asm volatile("" ::: "memory");
            }
            asm volatile("" ::: "memory");
            const int rs1 = ((t - 1) & 1) * (NB * 64);
            bf16x8 h1[2];
            h1[0] = *(const bf16x8*)(H1 + rs1 + roff[0]);
            h1[1] = *(const bf16x8*)(H1 + rs1 + roff[1]);

            f32x4 a[2];
#pragma unroll
            for (int tau = 0; tau < 2; ++tau) {
                f32x4 s = {0.f, 0.f, 0.f, 0.f};
                s = MFMA(Ah[tau][2], h1[0], s);        // Whh1 . h1(t-1)
                s = MFMA(Ah[tau][3], h1[1], s);
                a[tau] = p[tau] + s;
            }

            const f32x2 hv = cell2(a[0], a[1], &c1);
            if (t == TT - 1) {                  // exact fp32 h1(T-1) for FC
                h1fin[uu[0]][m] = hv[0];
                h1fin[uu[1]][m] = hv[1];
            }
            const int ws = (t & 1) * (NB * 64);
            H1[ws + woff[0]] = f32_to_bf16_rne(hv[0]);
            H1[ws + woff[1]] = f32_to_bf16_rne(hv[1]);

            asm volatile("s_waitcnt lgkmcnt(0)" ::: "memory");
            if (lane == 0) *(volatile int*)&f1[uW] = t;
        }
    }

    __syncthreads();

    // ---- FC epilogue: out[b] = h1(T-1)[b] . Wfc + bfc ----
    if (tid < NB) {
        float sacc = bfc[0];
#pragma unroll
        for (int u = 0; u < HH; ++u) sacc = fmaf(h1fin[u][tid], Wfc[u], sacc);
        out[b0 + tid] = sacc;
    }
}

extern "C" void kernel_launch(void* const* d_in, const int* in_sizes, int n_in,
                              void* d_out, int out_size, void* d_ws, size_t ws_size,
                              hipStream_t stream) {
    const float* x    = (const float*)d_in[0];
    const float* Wih0 = (const float*)d_in[1];
    const float* Whh0 = (const float*)d_in[2];
    const float* bih0 = (const float*)d_in[3];
    const float* bhh0 = (const float*)d_in[4];
    const float* Wih1 = (const float*)d_in[5];
    const float* Whh1 = (const float*)d_in[6];
    const float* bih1 = (const float*)d_in[7];
    const float* bhh1 = (const float*)d_in[8];
    const float* Wfc  = (const float*)d_in[9];
    const float* bfc  = (const float*)d_in[10];

    lstm_fast_kernel<<<dim3(4096 / NB), dim3(768), 0, stream>>>(
        x, Wih0, Whh0, bih0, bhh0, Wih1, Whh1, bih1, bhh1, Wfc, bfc, (float*)d_out);
}